// Round 8
// baseline (144.709 us; speedup 1.0000x reference)
//
#include <hip/hip_runtime.h>
#include <math.h>

#define NQ 12
#define DIM 4096
#define KS 6
#define BB 256
#define SEQ 128
#define DEMB 512

// Fused encoder + 6-step VQC sim + head. 512 threads, 8 amps/thread.
// TWO-PHASE step (2 LDS round-trips, 2 barriers, 0 fences):
//   L_A: j = r | lane<<3 | wave<<9   (reg: wires 11,10,9; lane masks 1,2,4
//        = wires 8,7,6; wave bits = wires 2,1,0)
//   L_E: j = wave | lane<<3 | r<<9   (reg: wires 2,1,0; lane masks 8,16,32
//        = wires 5,4,3)
// Step: [expval(prev post-ring, plain signs) ] phase1 gates -> A-image dump
// -> B1 -> [readout prev] gather L_E -> phase2 gates -> ring scatter -> B2
// -> gather L_A.  LDS phys: swz(j) = j ^ ((j>>4)&14).

#define REG_GATE(P, W) { \
    float4 c0 = *(const float4*)&s_u[k][W][0]; \
    float4 c1 = *(const float4*)&s_u[k][W][4]; \
    float u00r=c0.x,u00i=c0.y,u01r=c0.z,u01i=c0.w; \
    float u10r=c1.x,u10i=c1.y,u11r=c1.z,u11i=c1.w; \
    _Pragma("unroll") \
    for (int r0 = 0; r0 < 8; ++r0) if (!(r0 & (1 << (P)))) { \
        int r1 = r0 | (1 << (P)); \
        float2 A = a[r0], Bv = a[r1]; \
        a[r0].x = u00r*A.x - u00i*A.y + u01r*Bv.x - u01i*Bv.y; \
        a[r0].y = u00r*A.y + u00i*A.x + u01r*Bv.y + u01i*Bv.x; \
        a[r1].x = u10r*A.x - u10i*A.y + u11r*Bv.x - u11i*Bv.y; \
        a[r1].y = u10r*A.y + u10i*A.x + u11r*Bv.y + u11i*Bv.x; \
    } }

// single-qubit gate on a LANE bit (mask MK), same math as verified R2/R4 code
#define SHUF_GATE(MK, W) { \
    float4 c0 = *(const float4*)&s_u[k][W][0]; \
    float4 c1 = *(const float4*)&s_u[k][W][4]; \
    int bit_ = (lane & (MK)) != 0; \
    float c0r = bit_ ? c1.z : c0.x; \
    float c0i = bit_ ? c1.w : c0.y; \
    float c1r = bit_ ? c1.x : c0.z; \
    float c1i = bit_ ? c1.y : c0.w; \
    _Pragma("unroll") \
    for (int r = 0; r < 8; ++r) { \
        float px = __shfl_xor(a[r].x, MK, 64); \
        float py = __shfl_xor(a[r].y, MK, 64); \
        float nx = c0r*a[r].x - c0i*a[r].y + c1r*px - c1i*py; \
        float ny = c0r*a[r].y + c0i*a[r].x + c1r*py + c1i*px; \
        a[r].x = nx; a[r].y = ny; \
    } }

#define PL(v, m) v += __shfl_xor(v, m, 64);

__device__ __forceinline__ int swz14(int x) { return x ^ ((x >> 4) & 14); }

__global__ __launch_bounds__(512) void fused_kernel(
    const int* __restrict__ ids, const int* __restrict__ mask,
    const float* __restrict__ emb, const float* __restrict__ pw,
    const float* __restrict__ pb, const float* __restrict__ theta,
    const float* __restrict__ hw, const float* __restrict__ hb,
    float* __restrict__ readouts, float* __restrict__ logits,
    float* __restrict__ last)
{
    __shared__ __align__(16) float2 buf0[DIM];   // 32 KB
    __shared__ __align__(16) float2 buf1[DIM];   // 32 KB
    __shared__ __align__(16) float  s_u[KS][NQ][8];
    __shared__ float  s_red[8][NQ];
    __shared__ float  s_msum[4];
    __shared__ float  s_wred[2][NQ];
    __shared__ float  s_x[NQ];
    __shared__ float  s_hw[8 * NQ];
    __shared__ float  s_hb[8];

    int b = blockIdx.x;
    int tid = threadIdx.x;
    int lane = tid & 63, wave = tid >> 6;     // wave 0..7

    // ---------------- encoder ----------------
    int*   s_ids = (int*)buf1;
    float* s_m   = (float*)buf1 + SEQ;
    float4* s_part = (float4*)buf0;           // [4][128]

    if (tid < SEQ) {
        s_ids[tid] = ids[b * SEQ + tid];
        s_m[tid]   = (float)mask[b * SEQ + tid];
    }
    if (tid >= 256 && tid < 256 + 8 * NQ) s_hw[tid - 256] = hw[tid - 256];
    if (tid >= 384 && tid < 392)          s_hb[tid - 384] = hb[tid - 384];
    __syncthreads();

    {
        int g = tid >> 7, e = tid & 127;
        float4 acc = make_float4(0.f, 0.f, 0.f, 0.f);
        float msum = 0.f;
        #pragma unroll 8
        for (int s = g; s < SEQ; s += 4) {
            float m = s_m[s];
            float4 v = ((const float4*)emb)[(size_t)s_ids[s] * 128 + e];
            acc.x = fmaf(m, v.x, acc.x);
            acc.y = fmaf(m, v.y, acc.y);
            acc.z = fmaf(m, v.z, acc.z);
            acc.w = fmaf(m, v.w, acc.w);
            msum += m;
        }
        __syncthreads();   // ids/m reads done before buf0 overlay write
        s_part[g * 128 + e] = acc;
        if (e == 0) s_msum[g] = msum;
    }
    __syncthreads();

    if (tid < 128) {
        float tm = fmaxf(s_msum[0] + s_msum[1] + s_msum[2] + s_msum[3], 1.f);
        float inv = 1.f / tm;
        float4 p0 = s_part[0 * 128 + tid], p1 = s_part[1 * 128 + tid];
        float4 p2 = s_part[2 * 128 + tid], p3 = s_part[3 * 128 + tid];
        float4 p;
        p.x = (p0.x + p1.x + p2.x + p3.x) * inv;
        p.y = (p0.y + p1.y + p2.y + p3.y) * inv;
        p.z = (p0.z + p1.z + p2.z + p3.z) * inv;
        p.w = (p0.w + p1.w + p2.w + p3.w) * inv;
        float z[NQ];
        #pragma unroll
        for (int i = 0; i < NQ; ++i) {
            float4 w4 = ((const float4*)pw)[i * 128 + tid];
            z[i] = p.x * w4.x + p.y * w4.y + p.z * w4.z + p.w * w4.w;
        }
        #pragma unroll
        for (int i = 0; i < NQ; ++i) {
            #pragma unroll
            for (int off = 32; off > 0; off >>= 1)
                z[i] += __shfl_xor(z[i], off, 64);
        }
        if ((tid & 63) == 0) {
            int w = tid >> 6;
            #pragma unroll
            for (int i = 0; i < NQ; ++i) s_wred[w][i] = z[i];
        }
    }
    __syncthreads();
    if (tid < NQ) {
        float d = pb[tid] + s_wred[0][tid] + s_wred[1][tid];
        s_x[tid] = tanhf(d) * 3.14159274101257324f;
    }
    __syncthreads();

    // ---------------- gate matrices: U = Rot(phi,te,om) @ RY(x) ----------
    if (tid < KS * NQ) {
        int k = tid / NQ, w = tid % NQ;
        float ang = s_x[w];
        float cy = cosf(0.5f * ang), sy = sinf(0.5f * ang);
        const float* th = theta + (k * NQ + w) * 3;
        float phi = th[0], te = th[1], om = th[2];
        float ct = cosf(0.5f * te), st = sinf(0.5f * te);
        float a1 = -0.5f * (phi + om);
        float epr = cosf(a1), epi = sinf(a1);
        float a2 = 0.5f * (phi - om);
        float emr = cosf(a2), emi = sinf(a2);
        float R00r = epr * ct,  R00i = epi * ct;
        float R01r = -emr * st, R01i = -emi * st;
        float R10r = emr * st,  R10i = -emi * st;
        float R11r = epr * ct,  R11i = -epi * ct;
        s_u[k][w][0] =  R00r * cy + R01r * sy;
        s_u[k][w][1] =  R00i * cy + R01i * sy;
        s_u[k][w][2] = -R00r * sy + R01r * cy;
        s_u[k][w][3] = -R00i * sy + R01i * cy;
        s_u[k][w][4] =  R10r * cy + R11r * sy;
        s_u[k][w][5] =  R10i * cy + R11i * sy;
        s_u[k][w][6] = -R10r * sy + R11r * cy;
        s_u[k][w][7] = -R10i * sy + R11i * cy;
    }

    // ---------------- constant addresses ----------------
    int T8 = tid << 3;
    int baseA  = swz14(T8);
    int baseA4 = baseA >> 1;          // float4 index; elem i at baseA4^i
    int addrE[8], idxP[8];
    #pragma unroll
    for (int r = 0; r < 8; ++r) {
        int jE = wave | (lane << 3) | (r << 9);
        addrE[r] = swz14(jE);
        int b0 = (jE >> 11) & 1;
        int pref = b0, outv = 0;
        for (int w = 1; w < NQ; ++w) {
            pref ^= (jE >> (11 - w)) & 1;
            outv |= pref << (11 - w);
        }
        outv |= (b0 ^ pref) << 11;
        idxP[r] = swz14(outv);
    }

    float2 a[8];
    #pragma unroll
    for (int r = 0; r < 8; ++r) a[r] = make_float2(0.f, 0.f);
    if (tid == 0) a[0].x = 1.f;
    __syncthreads();   // s_u ready, enc buf reads done

    // ---------------- K steps ----------------
    for (int k = 0; k < KS; ++k) {
        // expvals of current regs (= post-ring state of step k-1), L_A layout
        if (k > 0) {
            float p[8];
            #pragma unroll
            for (int r = 0; r < 8; ++r)
                p[r] = a[r].x * a[r].x + a[r].y * a[r].y;
            float e0=p[0]+p[1], d0=p[0]-p[1], e1=p[2]+p[3], d1=p[2]-p[3];
            float e2=p[4]+p[5], d2=p[4]-p[5], e3=p[6]+p[7], d3=p[6]-p[7];
            float T   = e0+e1+e2+e3;
            float S11 = d0+d1+d2+d3;
            float S10 = (e0-e1)+(e2-e3);
            float S9  = (e0+e1)-(e2+e3);
            float c = T, x;
            x = __shfl_xor(c,1,64);  float V8=(lane&1)? x-c:c-x;  c+=x;
            PL(V8,2) PL(V8,4) PL(V8,8) PL(V8,16) PL(V8,32)
            x = __shfl_xor(c,2,64);  float V7=(lane&2)? x-c:c-x;  c+=x;
            PL(V7,4) PL(V7,8) PL(V7,16) PL(V7,32)
            x = __shfl_xor(c,4,64);  float V6=(lane&4)? x-c:c-x;  c+=x;
            PL(V6,8) PL(V6,16) PL(V6,32)
            x = __shfl_xor(c,8,64);  float V5=(lane&8)? x-c:c-x;  c+=x;
            PL(V5,16) PL(V5,32)
            x = __shfl_xor(c,16,64); float V4=(lane&16)? x-c:c-x; c+=x;
            PL(V4,32)
            x = __shfl_xor(c,32,64); float V3=(lane&32)? x-c:c-x; c+=x;
            PL(S11,1) PL(S11,2) PL(S11,4) PL(S11,8) PL(S11,16) PL(S11,32)
            PL(S10,1) PL(S10,2) PL(S10,4) PL(S10,8) PL(S10,16) PL(S10,32)
            PL(S9,1)  PL(S9,2)  PL(S9,4)  PL(S9,8)  PL(S9,16)  PL(S9,32)
            if (lane == 0) {
                float* sr = s_red[wave];
                sr[11] = S11; sr[10] = S10; sr[9] = S9;
                sr[8] = V8; sr[7] = V7; sr[6] = V6;
                sr[5] = V5; sr[4] = V4; sr[3] = V3;
                sr[2] = (wave & 1) ? -c : c;
                sr[1] = (wave & 2) ? -c : c;
                sr[0] = (wave & 4) ? -c : c;
            }
        }

        // phase 1 (L_A): reg gates 11,10,9 + lane gates 8,7,6
        REG_GATE(0, 11) REG_GATE(1, 10) REG_GATE(2, 9)
        SHUF_GATE(1, 8) SHUF_GATE(2, 7) SHUF_GATE(4, 6)

        // dump A-image (b128)
        #pragma unroll
        for (int i = 0; i < 4; ++i)
            ((float4*)buf0)[baseA4 ^ i] =
                make_float4(a[2*i].x, a[2*i].y, a[2*i+1].x, a[2*i+1].y);
        __syncthreads();                                   // B1

        // readout of step k-1 (s_red writes ordered by B1)
        if (k > 0) {
            if (tid < NQ) {
                float s = 0.f;
                #pragma unroll
                for (int w2 = 0; w2 < 8; ++w2) s += s_red[w2][tid];
                readouts[((k-1) * BB + b) * NQ + tid] = s;
            }
            if (tid < 8) {
                float acc2 = s_hb[tid];
                #pragma unroll
                for (int i = 0; i < NQ; ++i) {
                    float si = 0.f;
                    #pragma unroll
                    for (int w2 = 0; w2 < 8; ++w2) si += s_red[w2][i];
                    acc2 = fmaf(si, s_hw[tid * NQ + i], acc2);
                }
                logits[((k-1) * BB + b) * 8 + tid] = acc2;
            }
        }

        // gather L_E
        #pragma unroll
        for (int r = 0; r < 8; ++r) a[r] = buf0[addrE[r]];

        // phase 2 (L_E): reg gates 2,1,0 + lane gates 5,4,3
        REG_GATE(0, 2) REG_GATE(1, 1) REG_GATE(2, 0)
        SHUF_GATE(8, 5) SHUF_GATE(16, 4) SHUF_GATE(32, 3)

        // CNOT-ring permutation scatter
        #pragma unroll
        for (int r = 0; r < 8; ++r) buf1[idxP[r]] = a[r];
        __syncthreads();                                   // B2
        #pragma unroll
        for (int i = 0; i < 4; ++i) {
            float4 v = ((float4*)buf1)[baseA4 ^ i];
            a[2*i]   = make_float2(v.x, v.y);
            a[2*i+1] = make_float2(v.z, v.w);
        }
    }

    // final expvals (post-ring of step KS-1) + readout
    {
        float p[8];
        #pragma unroll
        for (int r = 0; r < 8; ++r)
            p[r] = a[r].x * a[r].x + a[r].y * a[r].y;
        float e0=p[0]+p[1], d0=p[0]-p[1], e1=p[2]+p[3], d1=p[2]-p[3];
        float e2=p[4]+p[5], d2=p[4]-p[5], e3=p[6]+p[7], d3=p[6]-p[7];
        float T   = e0+e1+e2+e3;
        float S11 = d0+d1+d2+d3;
        float S10 = (e0-e1)+(e2-e3);
        float S9  = (e0+e1)-(e2+e3);
        float c = T, x;
        x = __shfl_xor(c,1,64);  float V8=(lane&1)? x-c:c-x;  c+=x;
        PL(V8,2) PL(V8,4) PL(V8,8) PL(V8,16) PL(V8,32)
        x = __shfl_xor(c,2,64);  float V7=(lane&2)? x-c:c-x;  c+=x;
        PL(V7,4) PL(V7,8) PL(V7,16) PL(V7,32)
        x = __shfl_xor(c,4,64);  float V6=(lane&4)? x-c:c-x;  c+=x;
        PL(V6,8) PL(V6,16) PL(V6,32)
        x = __shfl_xor(c,8,64);  float V5=(lane&8)? x-c:c-x;  c+=x;
        PL(V5,16) PL(V5,32)
        x = __shfl_xor(c,16,64); float V4=(lane&16)? x-c:c-x; c+=x;
        PL(V4,32)
        x = __shfl_xor(c,32,64); float V3=(lane&32)? x-c:c-x; c+=x;
        PL(S11,1) PL(S11,2) PL(S11,4) PL(S11,8) PL(S11,16) PL(S11,32)
        PL(S10,1) PL(S10,2) PL(S10,4) PL(S10,8) PL(S10,16) PL(S10,32)
        PL(S9,1)  PL(S9,2)  PL(S9,4)  PL(S9,8)  PL(S9,16)  PL(S9,32)
        if (lane == 0) {
            float* sr = s_red[wave];
            sr[11] = S11; sr[10] = S10; sr[9] = S9;
            sr[8] = V8; sr[7] = V7; sr[6] = V6;
            sr[5] = V5; sr[4] = V4; sr[3] = V3;
            sr[2] = (wave & 1) ? -c : c;
            sr[1] = (wave & 2) ? -c : c;
            sr[0] = (wave & 4) ? -c : c;
        }
    }
    __syncthreads();
    if (tid < NQ) {
        float s = 0.f;
        #pragma unroll
        for (int w2 = 0; w2 < 8; ++w2) s += s_red[w2][tid];
        readouts[((KS-1) * BB + b) * NQ + tid] = s;
    }
    if (tid < 8) {
        float acc2 = s_hb[tid];
        #pragma unroll
        for (int i = 0; i < NQ; ++i) {
            float si = 0.f;
            #pragma unroll
            for (int w2 = 0; w2 < 8; ++w2) si += s_red[w2][i];
            acc2 = fmaf(si, s_hw[tid * NQ + i], acc2);
        }
        logits[((KS-1) * BB + b) * 8 + tid] = acc2;
        last[b * 8 + tid] = acc2;
    }
}

extern "C" void kernel_launch(void* const* d_in, const int* in_sizes, int n_in,
                              void* d_out, int out_size, void* d_ws, size_t ws_size,
                              hipStream_t stream) {
    const int*   ids   = (const int*)d_in[0];
    const int*   mask  = (const int*)d_in[1];
    const float* emb   = (const float*)d_in[2];
    const float* pw    = (const float*)d_in[3];
    const float* pb    = (const float*)d_in[4];
    const float* theta = (const float*)d_in[5];
    const float* hw    = (const float*)d_in[6];
    const float* hb    = (const float*)d_in[7];
    float* out = (float*)d_out;

    float* readouts = out + KS * BB * 8;              // [K,B,NQ]
    float* last     = out + KS * BB * 8 + KS * BB * NQ;

    fused_kernel<<<BB, 512, 0, stream>>>(ids, mask, emb, pw, pb, theta,
                                         hw, hb, readouts, out, last);
}

// Round 9
// 141.488 us; speedup vs baseline: 1.0228x; 1.0228x over previous
//
#include <hip/hip_runtime.h>
#include <math.h>

#define NQ 12
#define DIM 4096
#define KS 6
#define BB 256
#define SEQ 128
#define DEMB 512

// Fused encoder + 6-step VQC sim + head. 512 threads, 8 amps/thread.
// Two-phase step, 2 LDS round-trips, 2 barriers. Lane-bit gates on masks
// 1,2 use DPP quad_perm (pure VALU, no LDS); only mask-4 gates + part of
// the expval tree use the LDS pipe.
//   L_A : j = r | lane<<3 | wave<<9   (reg: wires 11,10,9; lane m1,2,4 =
//         wires 8,7,6; wave bits = wires 2,1,0)
//   L_E': j = wave | ((lane>>3)&7)<<3 | (lane&7)<<6 | r<<9
//         (reg: wires 2,1,0; lane m1,2,4 = wires 5,4,3)
// LDS phys: swz(j) = j ^ ((j>>4)&14) — all patterns conflict-free.

#define DPP_XOR1(v) __int_as_float(__builtin_amdgcn_mov_dpp(__float_as_int(v), 0xB1, 0xF, 0xF, true))
#define DPP_XOR2(v) __int_as_float(__builtin_amdgcn_mov_dpp(__float_as_int(v), 0x4E, 0xF, 0xF, true))

#define REG_GATE(P, W) { \
    float4 c0 = *(const float4*)&s_u[k][W][0]; \
    float4 c1 = *(const float4*)&s_u[k][W][4]; \
    float u00r=c0.x,u00i=c0.y,u01r=c0.z,u01i=c0.w; \
    float u10r=c1.x,u10i=c1.y,u11r=c1.z,u11i=c1.w; \
    _Pragma("unroll") \
    for (int r0 = 0; r0 < 8; ++r0) if (!(r0 & (1 << (P)))) { \
        int r1 = r0 | (1 << (P)); \
        float2 A = a[r0], Bv = a[r1]; \
        a[r0].x = u00r*A.x - u00i*A.y + u01r*Bv.x - u01i*Bv.y; \
        a[r0].y = u00r*A.y + u00i*A.x + u01r*Bv.y + u01i*Bv.x; \
        a[r1].x = u10r*A.x - u10i*A.y + u11r*Bv.x - u11i*Bv.y; \
        a[r1].y = u10r*A.y + u10i*A.x + u11r*Bv.y + u11i*Bv.x; \
    } }

// lane-bit gate via generic shuffle (LDS pipe) — used for mask 4
#define SHUF_GATE(MK, W) { \
    float4 c0 = *(const float4*)&s_u[k][W][0]; \
    float4 c1 = *(const float4*)&s_u[k][W][4]; \
    int bit_ = (lane & (MK)) != 0; \
    float c0r = bit_ ? c1.z : c0.x; \
    float c0i = bit_ ? c1.w : c0.y; \
    float c1r = bit_ ? c1.x : c0.z; \
    float c1i = bit_ ? c1.y : c0.w; \
    _Pragma("unroll") \
    for (int r = 0; r < 8; ++r) { \
        float px = __shfl_xor(a[r].x, MK, 64); \
        float py = __shfl_xor(a[r].y, MK, 64); \
        float nx = c0r*a[r].x - c0i*a[r].y + c1r*px - c1i*py; \
        float ny = c0r*a[r].y + c0i*a[r].x + c1r*py + c1i*px; \
        a[r].x = nx; a[r].y = ny; \
    } }

// lane-bit gate via DPP quad_perm (VALU only) — masks 1,2
#define DPP_GATE(MK, W, DPPF) { \
    float4 c0 = *(const float4*)&s_u[k][W][0]; \
    float4 c1 = *(const float4*)&s_u[k][W][4]; \
    int bit_ = (lane & (MK)) != 0; \
    float c0r = bit_ ? c1.z : c0.x; \
    float c0i = bit_ ? c1.w : c0.y; \
    float c1r = bit_ ? c1.x : c0.z; \
    float c1i = bit_ ? c1.y : c0.w; \
    _Pragma("unroll") \
    for (int r = 0; r < 8; ++r) { \
        float px = DPPF(a[r].x); \
        float py = DPPF(a[r].y); \
        float nx = c0r*a[r].x - c0i*a[r].y + c1r*px - c1i*py; \
        float ny = c0r*a[r].y + c0i*a[r].x + c1r*py + c1i*px; \
        a[r].x = nx; a[r].y = ny; \
    } }

#define PL(v, m) v += __shfl_xor(v, m, 64);

__device__ __forceinline__ int swz14(int x) { return x ^ ((x >> 4) & 14); }

// expvals from L_A-layout regs (post-ring state); writes s_red[wave][*]
__device__ __forceinline__ void expval_LA(const float2* a, int lane, int wave,
                                          float sr[][NQ]) {
    float p[8];
    #pragma unroll
    for (int r = 0; r < 8; ++r)
        p[r] = a[r].x * a[r].x + a[r].y * a[r].y;
    float e0=p[0]+p[1], d0=p[0]-p[1], e1=p[2]+p[3], d1=p[2]-p[3];
    float e2=p[4]+p[5], d2=p[4]-p[5], e3=p[6]+p[7], d3=p[6]-p[7];
    float T   = e0+e1+e2+e3;
    float S11 = d0+d1+d2+d3;
    float S10 = (e0-e1)+(e2-e3);
    float S9  = (e0+e1)-(e2+e3);
    float c = T, x;
    x = DPP_XOR1(c);        float V8=(lane&1)? x-c:c-x;  c+=x;
    V8 += DPP_XOR2(V8); PL(V8,4) PL(V8,8) PL(V8,16) PL(V8,32)
    x = DPP_XOR2(c);        float V7=(lane&2)? x-c:c-x;  c+=x;
    PL(V7,4) PL(V7,8) PL(V7,16) PL(V7,32)
    x = __shfl_xor(c,4,64);  float V6=(lane&4)? x-c:c-x;  c+=x;
    PL(V6,8) PL(V6,16) PL(V6,32)
    x = __shfl_xor(c,8,64);  float V5=(lane&8)? x-c:c-x;  c+=x;
    PL(V5,16) PL(V5,32)
    x = __shfl_xor(c,16,64); float V4=(lane&16)? x-c:c-x; c+=x;
    PL(V4,32)
    x = __shfl_xor(c,32,64); float V3=(lane&32)? x-c:c-x; c+=x;
    S11 += DPP_XOR1(S11); S11 += DPP_XOR2(S11);
    PL(S11,4) PL(S11,8) PL(S11,16) PL(S11,32)
    S10 += DPP_XOR1(S10); S10 += DPP_XOR2(S10);
    PL(S10,4) PL(S10,8) PL(S10,16) PL(S10,32)
    S9  += DPP_XOR1(S9);  S9  += DPP_XOR2(S9);
    PL(S9,4)  PL(S9,8)  PL(S9,16)  PL(S9,32)
    if (lane == 0) {
        float* o = sr[wave];
        o[11] = S11; o[10] = S10; o[9] = S9;
        o[8] = V8; o[7] = V7; o[6] = V6;
        o[5] = V5; o[4] = V4; o[3] = V3;
        o[2] = (wave & 1) ? -c : c;
        o[1] = (wave & 2) ? -c : c;
        o[0] = (wave & 4) ? -c : c;
    }
}

__global__ __launch_bounds__(512) void fused_kernel(
    const int* __restrict__ ids, const int* __restrict__ mask,
    const float* __restrict__ emb, const float* __restrict__ pw,
    const float* __restrict__ pb, const float* __restrict__ theta,
    const float* __restrict__ hw, const float* __restrict__ hb,
    float* __restrict__ readouts, float* __restrict__ logits,
    float* __restrict__ last)
{
    __shared__ __align__(16) float2 buf0[DIM];   // 32 KB
    __shared__ __align__(16) float2 buf1[DIM];   // 32 KB
    __shared__ __align__(16) float  s_u[KS][NQ][8];
    __shared__ float  s_red[8][NQ];
    __shared__ float  s_msum[4];
    __shared__ float  s_wred[2][NQ];
    __shared__ float  s_x[NQ];
    __shared__ float  s_hw[8 * NQ];
    __shared__ float  s_hb[8];

    int b = blockIdx.x;
    int tid = threadIdx.x;
    int lane = tid & 63, wave = tid >> 6;     // wave 0..7

    // ---------------- encoder ----------------
    int*   s_ids = (int*)buf1;
    float* s_m   = (float*)buf1 + SEQ;
    float4* s_part = (float4*)buf0;           // [4][128]

    if (tid < SEQ) {
        s_ids[tid] = ids[b * SEQ + tid];
        s_m[tid]   = (float)mask[b * SEQ + tid];
    }
    if (tid >= 256 && tid < 256 + 8 * NQ) s_hw[tid - 256] = hw[tid - 256];
    if (tid >= 384 && tid < 392)          s_hb[tid - 384] = hb[tid - 384];
    __syncthreads();

    {
        int g = tid >> 7, e = tid & 127;
        float4 acc0 = make_float4(0.f, 0.f, 0.f, 0.f);
        float4 acc1 = make_float4(0.f, 0.f, 0.f, 0.f);
        float msum = 0.f;
        const float4* emb4 = (const float4*)emb;
        #pragma unroll 8
        for (int t = 0; t < 32; t += 2) {
            int sA = g + 4 * t, sB = sA + 4;
            float mA = s_m[sA], mB = s_m[sB];
            float4 vA = emb4[(size_t)s_ids[sA] * 128 + e];
            float4 vB = emb4[(size_t)s_ids[sB] * 128 + e];
            acc0.x = fmaf(mA, vA.x, acc0.x); acc0.y = fmaf(mA, vA.y, acc0.y);
            acc0.z = fmaf(mA, vA.z, acc0.z); acc0.w = fmaf(mA, vA.w, acc0.w);
            acc1.x = fmaf(mB, vB.x, acc1.x); acc1.y = fmaf(mB, vB.y, acc1.y);
            acc1.z = fmaf(mB, vB.z, acc1.z); acc1.w = fmaf(mB, vB.w, acc1.w);
            msum += mA + mB;
        }
        acc0.x += acc1.x; acc0.y += acc1.y;
        acc0.z += acc1.z; acc0.w += acc1.w;
        __syncthreads();   // ids/m reads done before buf0 overlay write
        s_part[g * 128 + e] = acc0;
        if (e == 0) s_msum[g] = msum;
    }
    __syncthreads();

    if (tid < 128) {
        float tm = fmaxf(s_msum[0] + s_msum[1] + s_msum[2] + s_msum[3], 1.f);
        float inv = 1.f / tm;
        float4 p0 = s_part[0 * 128 + tid], p1 = s_part[1 * 128 + tid];
        float4 p2 = s_part[2 * 128 + tid], p3 = s_part[3 * 128 + tid];
        float4 p;
        p.x = (p0.x + p1.x + p2.x + p3.x) * inv;
        p.y = (p0.y + p1.y + p2.y + p3.y) * inv;
        p.z = (p0.z + p1.z + p2.z + p3.z) * inv;
        p.w = (p0.w + p1.w + p2.w + p3.w) * inv;
        float z[NQ];
        #pragma unroll
        for (int i = 0; i < NQ; ++i) {
            float4 w4 = ((const float4*)pw)[i * 128 + tid];
            z[i] = p.x * w4.x + p.y * w4.y + p.z * w4.z + p.w * w4.w;
        }
        #pragma unroll
        for (int i = 0; i < NQ; ++i) {
            #pragma unroll
            for (int off = 32; off > 0; off >>= 1)
                z[i] += __shfl_xor(z[i], off, 64);
        }
        if ((tid & 63) == 0) {
            int w = tid >> 6;
            #pragma unroll
            for (int i = 0; i < NQ; ++i) s_wred[w][i] = z[i];
        }
    }
    __syncthreads();
    if (tid < NQ) {
        float d = pb[tid] + s_wred[0][tid] + s_wred[1][tid];
        s_x[tid] = tanhf(d) * 3.14159274101257324f;
    }
    __syncthreads();

    // ---------------- gate matrices: U = Rot(phi,te,om) @ RY(x) ----------
    if (tid < KS * NQ) {
        int k = tid / NQ, w = tid % NQ;
        float ang = s_x[w];
        float cy = cosf(0.5f * ang), sy = sinf(0.5f * ang);
        const float* th = theta + (k * NQ + w) * 3;
        float phi = th[0], te = th[1], om = th[2];
        float ct = cosf(0.5f * te), st = sinf(0.5f * te);
        float a1 = -0.5f * (phi + om);
        float epr = cosf(a1), epi = sinf(a1);
        float a2 = 0.5f * (phi - om);
        float emr = cosf(a2), emi = sinf(a2);
        float R00r = epr * ct,  R00i = epi * ct;
        float R01r = -emr * st, R01i = -emi * st;
        float R10r = emr * st,  R10i = -emi * st;
        float R11r = epr * ct,  R11i = -epi * ct;
        s_u[k][w][0] =  R00r * cy + R01r * sy;
        s_u[k][w][1] =  R00i * cy + R01i * sy;
        s_u[k][w][2] = -R00r * sy + R01r * cy;
        s_u[k][w][3] = -R00i * sy + R01i * cy;
        s_u[k][w][4] =  R10r * cy + R11r * sy;
        s_u[k][w][5] =  R10i * cy + R11i * sy;
        s_u[k][w][6] = -R10r * sy + R11r * cy;
        s_u[k][w][7] = -R10i * sy + R11i * cy;
    }

    // ---------------- constant addresses ----------------
    int T8 = tid << 3;
    int baseA  = swz14(T8);
    int baseA4 = baseA >> 1;          // float4 index; elem i at baseA4^i
    int addrE[8], idxP[8];
    #pragma unroll
    for (int r = 0; r < 8; ++r) {
        int jE = wave | (((lane >> 3) & 7) << 3) | ((lane & 7) << 6) | (r << 9);
        addrE[r] = swz14(jE);
        int b0 = (jE >> 11) & 1;
        int pref = b0, outv = 0;
        for (int w = 1; w < NQ; ++w) {
            pref ^= (jE >> (11 - w)) & 1;
            outv |= pref << (11 - w);
        }
        outv |= (b0 ^ pref) << 11;
        idxP[r] = swz14(outv);
    }

    float2 a[8];
    #pragma unroll
    for (int r = 0; r < 8; ++r) a[r] = make_float2(0.f, 0.f);
    if (tid == 0) a[0].x = 1.f;
    __syncthreads();   // s_u ready, enc buf reads done

    // ---------------- K steps ----------------
    for (int k = 0; k < KS; ++k) {
        // expvals of current regs (= post-ring state of step k-1), L_A layout
        if (k > 0) expval_LA(a, lane, wave, s_red);

        // phase 1 (L_A): reg 11,10,9; DPP m1->w8, m2->w7; LDS m4->w6
        REG_GATE(0, 11) REG_GATE(1, 10) REG_GATE(2, 9)
        DPP_GATE(1, 8, DPP_XOR1)
        DPP_GATE(2, 7, DPP_XOR2)
        SHUF_GATE(4, 6)

        // dump A-image (b128)
        #pragma unroll
        for (int i = 0; i < 4; ++i)
            ((float4*)buf0)[baseA4 ^ i] =
                make_float4(a[2*i].x, a[2*i].y, a[2*i+1].x, a[2*i+1].y);
        __syncthreads();                                   // B1

        // readout of step k-1 (s_red writes ordered by B1)
        if (k > 0) {
            if (tid < NQ) {
                float s = 0.f;
                #pragma unroll
                for (int w2 = 0; w2 < 8; ++w2) s += s_red[w2][tid];
                readouts[((k-1) * BB + b) * NQ + tid] = s;
            }
            if (tid < 8) {
                float acc2 = s_hb[tid];
                #pragma unroll
                for (int i = 0; i < NQ; ++i) {
                    float si = 0.f;
                    #pragma unroll
                    for (int w2 = 0; w2 < 8; ++w2) si += s_red[w2][i];
                    acc2 = fmaf(si, s_hw[tid * NQ + i], acc2);
                }
                logits[((k-1) * BB + b) * 8 + tid] = acc2;
            }
        }

        // gather L_E'
        #pragma unroll
        for (int r = 0; r < 8; ++r) a[r] = buf0[addrE[r]];

        // phase 2 (L_E'): reg 2,1,0; DPP m1->w5, m2->w4; LDS m4->w3
        REG_GATE(0, 2) REG_GATE(1, 1) REG_GATE(2, 0)
        DPP_GATE(1, 5, DPP_XOR1)
        DPP_GATE(2, 4, DPP_XOR2)
        SHUF_GATE(4, 3)

        // CNOT-ring permutation scatter
        #pragma unroll
        for (int r = 0; r < 8; ++r) buf1[idxP[r]] = a[r];
        __syncthreads();                                   // B2
        #pragma unroll
        for (int i = 0; i < 4; ++i) {
            float4 v = ((float4*)buf1)[baseA4 ^ i];
            a[2*i]   = make_float2(v.x, v.y);
            a[2*i+1] = make_float2(v.z, v.w);
        }
    }

    // final expvals (post-ring of step KS-1) + readout
    expval_LA(a, lane, wave, s_red);
    __syncthreads();
    if (tid < NQ) {
        float s = 0.f;
        #pragma unroll
        for (int w2 = 0; w2 < 8; ++w2) s += s_red[w2][tid];
        readouts[((KS-1) * BB + b) * NQ + tid] = s;
    }
    if (tid < 8) {
        float acc2 = s_hb[tid];
        #pragma unroll
        for (int i = 0; i < NQ; ++i) {
            float si = 0.f;
            #pragma unroll
            for (int w2 = 0; w2 < 8; ++w2) si += s_red[w2][i];
            acc2 = fmaf(si, s_hw[tid * NQ + i], acc2);
        }
        logits[((KS-1) * BB + b) * 8 + tid] = acc2;
        last[b * 8 + tid] = acc2;
    }
}

extern "C" void kernel_launch(void* const* d_in, const int* in_sizes, int n_in,
                              void* d_out, int out_size, void* d_ws, size_t ws_size,
                              hipStream_t stream) {
    const int*   ids   = (const int*)d_in[0];
    const int*   mask  = (const int*)d_in[1];
    const float* emb   = (const float*)d_in[2];
    const float* pw    = (const float*)d_in[3];
    const float* pb    = (const float*)d_in[4];
    const float* theta = (const float*)d_in[5];
    const float* hw    = (const float*)d_in[6];
    const float* hb    = (const float*)d_in[7];
    float* out = (float*)d_out;

    float* readouts = out + KS * BB * 8;              // [K,B,NQ]
    float* last     = out + KS * BB * 8 + KS * BB * NQ;

    fused_kernel<<<BB, 512, 0, stream>>>(ids, mask, emb, pw, pb, theta,
                                         hw, hb, readouts, out, last);
}

// Round 10
// 141.067 us; speedup vs baseline: 1.0258x; 1.0030x over previous
//
#include <hip/hip_runtime.h>
#include <math.h>

#define NQ 12
#define DIM 4096
#define KS 6
#define BB 256
#define SEQ 128
#define DEMB 512

// Fused encoder + 6-step VQC sim + head. 512 threads, 8 amps/thread.
// Two-phase step, 2 LDS round-trips, 2 barriers. DPP quad_perm for lane
// masks 1,2; LDS shuffle only for mask 4. Coefficients hoisted per phase
// (one lgkm wait); all global output stores deferred to kernel end.
//   L_A : j = r | lane<<3 | wave<<9
//   L_E': j = wave | ((lane>>3)&7)<<3 | (lane&7)<<6 | r<<9
// LDS phys: swz(j) = j ^ ((j>>4)&14).

#define DPP_XOR1(v) __int_as_float(__builtin_amdgcn_mov_dpp(__float_as_int(v), 0xB1, 0xF, 0xF, true))
#define DPP_XOR2(v) __int_as_float(__builtin_amdgcn_mov_dpp(__float_as_int(v), 0x4E, 0xF, 0xF, true))

#define REG_GATE_C(P, C0, C1) { \
    float u00r=C0.x,u00i=C0.y,u01r=C0.z,u01i=C0.w; \
    float u10r=C1.x,u10i=C1.y,u11r=C1.z,u11i=C1.w; \
    _Pragma("unroll") \
    for (int r0 = 0; r0 < 8; ++r0) if (!(r0 & (1 << (P)))) { \
        int r1 = r0 | (1 << (P)); \
        float2 A = a[r0], Bv = a[r1]; \
        a[r0].x = u00r*A.x - u00i*A.y + u01r*Bv.x - u01i*Bv.y; \
        a[r0].y = u00r*A.y + u00i*A.x + u01r*Bv.y + u01i*Bv.x; \
        a[r1].x = u10r*A.x - u10i*A.y + u11r*Bv.x - u11i*Bv.y; \
        a[r1].y = u10r*A.y + u10i*A.x + u11r*Bv.y + u11i*Bv.x; \
    } }

#define SHUF_GATE_C(MK, C0, C1) { \
    int bit_ = (lane & (MK)) != 0; \
    float c0r = bit_ ? C1.z : C0.x; \
    float c0i = bit_ ? C1.w : C0.y; \
    float c1r = bit_ ? C1.x : C0.z; \
    float c1i = bit_ ? C1.y : C0.w; \
    _Pragma("unroll") \
    for (int r = 0; r < 8; ++r) { \
        float px = __shfl_xor(a[r].x, MK, 64); \
        float py = __shfl_xor(a[r].y, MK, 64); \
        float nx = c0r*a[r].x - c0i*a[r].y + c1r*px - c1i*py; \
        float ny = c0r*a[r].y + c0i*a[r].x + c1r*py + c1i*px; \
        a[r].x = nx; a[r].y = ny; \
    } }

#define DPP_GATE_C(MK, C0, C1, DPPF) { \
    int bit_ = (lane & (MK)) != 0; \
    float c0r = bit_ ? C1.z : C0.x; \
    float c0i = bit_ ? C1.w : C0.y; \
    float c1r = bit_ ? C1.x : C0.z; \
    float c1i = bit_ ? C1.y : C0.w; \
    _Pragma("unroll") \
    for (int r = 0; r < 8; ++r) { \
        float px = DPPF(a[r].x); \
        float py = DPPF(a[r].y); \
        float nx = c0r*a[r].x - c0i*a[r].y + c1r*px - c1i*py; \
        float ny = c0r*a[r].y + c0i*a[r].x + c1r*py + c1i*px; \
        a[r].x = nx; a[r].y = ny; \
    } }

#define PL(v, m) v += __shfl_xor(v, m, 64);

__device__ __forceinline__ int swz14(int x) { return x ^ ((x >> 4) & 14); }

// expvals from L_A-layout regs (post-ring state); writes s_red[wave][*]
__device__ __forceinline__ void expval_LA(const float2* a, int lane, int wave,
                                          float sr[][NQ]) {
    float p[8];
    #pragma unroll
    for (int r = 0; r < 8; ++r)
        p[r] = a[r].x * a[r].x + a[r].y * a[r].y;
    float e0=p[0]+p[1], d0=p[0]-p[1], e1=p[2]+p[3], d1=p[2]-p[3];
    float e2=p[4]+p[5], d2=p[4]-p[5], e3=p[6]+p[7], d3=p[6]-p[7];
    float T   = e0+e1+e2+e3;
    float S11 = d0+d1+d2+d3;
    float S10 = (e0-e1)+(e2-e3);
    float S9  = (e0+e1)-(e2+e3);
    float c = T, x;
    x = DPP_XOR1(c);        float V8=(lane&1)? x-c:c-x;  c+=x;
    V8 += DPP_XOR2(V8); PL(V8,4) PL(V8,8) PL(V8,16) PL(V8,32)
    x = DPP_XOR2(c);        float V7=(lane&2)? x-c:c-x;  c+=x;
    PL(V7,4) PL(V7,8) PL(V7,16) PL(V7,32)
    x = __shfl_xor(c,4,64);  float V6=(lane&4)? x-c:c-x;  c+=x;
    PL(V6,8) PL(V6,16) PL(V6,32)
    x = __shfl_xor(c,8,64);  float V5=(lane&8)? x-c:c-x;  c+=x;
    PL(V5,16) PL(V5,32)
    x = __shfl_xor(c,16,64); float V4=(lane&16)? x-c:c-x; c+=x;
    PL(V4,32)
    x = __shfl_xor(c,32,64); float V3=(lane&32)? x-c:c-x; c+=x;
    S11 += DPP_XOR1(S11); S11 += DPP_XOR2(S11);
    PL(S11,4) PL(S11,8) PL(S11,16) PL(S11,32)
    S10 += DPP_XOR1(S10); S10 += DPP_XOR2(S10);
    PL(S10,4) PL(S10,8) PL(S10,16) PL(S10,32)
    S9  += DPP_XOR1(S9);  S9  += DPP_XOR2(S9);
    PL(S9,4)  PL(S9,8)  PL(S9,16)  PL(S9,32)
    if (lane == 0) {
        float* o = sr[wave];
        o[11] = S11; o[10] = S10; o[9] = S9;
        o[8] = V8; o[7] = V7; o[6] = V6;
        o[5] = V5; o[4] = V4; o[3] = V3;
        o[2] = (wave & 1) ? -c : c;
        o[1] = (wave & 2) ? -c : c;
        o[0] = (wave & 4) ? -c : c;
    }
}

__global__ __launch_bounds__(512) void fused_kernel(
    const int* __restrict__ ids, const int* __restrict__ mask,
    const float* __restrict__ emb, const float* __restrict__ pw,
    const float* __restrict__ pb, const float* __restrict__ theta,
    const float* __restrict__ hw, const float* __restrict__ hb,
    float* __restrict__ readouts, float* __restrict__ logits,
    float* __restrict__ last)
{
    __shared__ __align__(16) float2 buf0[DIM];   // 32 KB
    __shared__ __align__(16) float2 buf1[DIM];   // 32 KB
    __shared__ __align__(16) float  s_u[KS][NQ][8];
    __shared__ float  s_red[8][NQ];
    __shared__ float  s_zk[KS][NQ];
    __shared__ float  s_msum[4];
    __shared__ float  s_wred[2][NQ];
    __shared__ float  s_x[NQ];
    __shared__ float  s_hw[8 * NQ];
    __shared__ float  s_hb[8];

    int b = blockIdx.x;
    int tid = threadIdx.x;
    int lane = tid & 63, wave = tid >> 6;     // wave 0..7

    // ---------------- encoder ----------------
    int*   s_ids = (int*)buf1;
    float* s_m   = (float*)buf1 + SEQ;
    float4* s_part = (float4*)buf0;           // [4][128]

    if (tid < SEQ) {
        s_ids[tid] = ids[b * SEQ + tid];
        s_m[tid]   = (float)mask[b * SEQ + tid];
    }
    if (tid >= 256 && tid < 256 + 8 * NQ) s_hw[tid - 256] = hw[tid - 256];
    if (tid >= 384 && tid < 392)          s_hb[tid - 384] = hb[tid - 384];
    __syncthreads();

    {
        int g = tid >> 7, e = tid & 127;
        float4 acc0 = make_float4(0.f, 0.f, 0.f, 0.f);
        float4 acc1 = make_float4(0.f, 0.f, 0.f, 0.f);
        float msum = 0.f;
        const float4* emb4 = (const float4*)emb;
        #pragma unroll 8
        for (int t = 0; t < 32; t += 2) {
            int sA = g + 4 * t, sB = sA + 4;
            float mA = s_m[sA], mB = s_m[sB];
            float4 vA = emb4[(size_t)s_ids[sA] * 128 + e];
            float4 vB = emb4[(size_t)s_ids[sB] * 128 + e];
            acc0.x = fmaf(mA, vA.x, acc0.x); acc0.y = fmaf(mA, vA.y, acc0.y);
            acc0.z = fmaf(mA, vA.z, acc0.z); acc0.w = fmaf(mA, vA.w, acc0.w);
            acc1.x = fmaf(mB, vB.x, acc1.x); acc1.y = fmaf(mB, vB.y, acc1.y);
            acc1.z = fmaf(mB, vB.z, acc1.z); acc1.w = fmaf(mB, vB.w, acc1.w);
            msum += mA + mB;
        }
        acc0.x += acc1.x; acc0.y += acc1.y;
        acc0.z += acc1.z; acc0.w += acc1.w;
        __syncthreads();   // ids/m reads done before buf0 overlay write
        s_part[g * 128 + e] = acc0;
        if (e == 0) s_msum[g] = msum;
    }
    __syncthreads();

    if (tid < 128) {
        float tm = fmaxf(s_msum[0] + s_msum[1] + s_msum[2] + s_msum[3], 1.f);
        float inv = 1.f / tm;
        float4 p0 = s_part[0 * 128 + tid], p1 = s_part[1 * 128 + tid];
        float4 p2 = s_part[2 * 128 + tid], p3 = s_part[3 * 128 + tid];
        float4 p;
        p.x = (p0.x + p1.x + p2.x + p3.x) * inv;
        p.y = (p0.y + p1.y + p2.y + p3.y) * inv;
        p.z = (p0.z + p1.z + p2.z + p3.z) * inv;
        p.w = (p0.w + p1.w + p2.w + p3.w) * inv;
        float z[NQ];
        #pragma unroll
        for (int i = 0; i < NQ; ++i) {
            float4 w4 = ((const float4*)pw)[i * 128 + tid];
            z[i] = p.x * w4.x + p.y * w4.y + p.z * w4.z + p.w * w4.w;
        }
        #pragma unroll
        for (int i = 0; i < NQ; ++i) {
            #pragma unroll
            for (int off = 32; off > 0; off >>= 1)
                z[i] += __shfl_xor(z[i], off, 64);
        }
        if ((tid & 63) == 0) {
            int w = tid >> 6;
            #pragma unroll
            for (int i = 0; i < NQ; ++i) s_wred[w][i] = z[i];
        }
    }
    __syncthreads();
    if (tid < NQ) {
        float d = pb[tid] + s_wred[0][tid] + s_wred[1][tid];
        s_x[tid] = tanhf(d) * 3.14159274101257324f;
    }
    __syncthreads();

    // ---------------- gate matrices: U = Rot(phi,te,om) @ RY(x) ----------
    if (tid < KS * NQ) {
        int k = tid / NQ, w = tid % NQ;
        float ang = s_x[w];
        float cy = cosf(0.5f * ang), sy = sinf(0.5f * ang);
        const float* th = theta + (k * NQ + w) * 3;
        float phi = th[0], te = th[1], om = th[2];
        float ct = cosf(0.5f * te), st = sinf(0.5f * te);
        float a1 = -0.5f * (phi + om);
        float epr = cosf(a1), epi = sinf(a1);
        float a2 = 0.5f * (phi - om);
        float emr = cosf(a2), emi = sinf(a2);
        float R00r = epr * ct,  R00i = epi * ct;
        float R01r = -emr * st, R01i = -emi * st;
        float R10r = emr * st,  R10i = -emi * st;
        float R11r = epr * ct,  R11i = -epi * ct;
        s_u[k][w][0] =  R00r * cy + R01r * sy;
        s_u[k][w][1] =  R00i * cy + R01i * sy;
        s_u[k][w][2] = -R00r * sy + R01r * cy;
        s_u[k][w][3] = -R00i * sy + R01i * cy;
        s_u[k][w][4] =  R10r * cy + R11r * sy;
        s_u[k][w][5] =  R10i * cy + R11i * sy;
        s_u[k][w][6] = -R10r * sy + R11r * cy;
        s_u[k][w][7] = -R10i * sy + R11i * cy;
    }

    // ---------------- constant addresses ----------------
    int T8 = tid << 3;
    int baseA  = swz14(T8);
    int baseA4 = baseA >> 1;          // float4 index; elem i at baseA4^i
    int addrE[8], idxP[8];
    #pragma unroll
    for (int r = 0; r < 8; ++r) {
        int jE = wave | (((lane >> 3) & 7) << 3) | ((lane & 7) << 6) | (r << 9);
        addrE[r] = swz14(jE);
        int b0 = (jE >> 11) & 1;
        int pref = b0, outv = 0;
        for (int w = 1; w < NQ; ++w) {
            pref ^= (jE >> (11 - w)) & 1;
            outv |= pref << (11 - w);
        }
        outv |= (b0 ^ pref) << 11;
        idxP[r] = swz14(outv);
    }

    float2 a[8];
    #pragma unroll
    for (int r = 0; r < 8; ++r) a[r] = make_float2(0.f, 0.f);
    if (tid == 0) a[0].x = 1.f;
    __syncthreads();   // s_u ready, enc buf reads done

    // ---------------- K steps ----------------
    #pragma unroll
    for (int k = 0; k < KS; ++k) {
        // expvals of current regs (= post-ring state of step k-1), L_A layout
        if (k > 0) expval_LA(a, lane, wave, s_red);

        // hoist phase-1 coefficients (wires 11,10,9,8,7,6) — one lgkm wait
        float4 c0a = *(const float4*)&s_u[k][11][0], c0b = *(const float4*)&s_u[k][11][4];
        float4 c1a = *(const float4*)&s_u[k][10][0], c1b = *(const float4*)&s_u[k][10][4];
        float4 c2a = *(const float4*)&s_u[k][ 9][0], c2b = *(const float4*)&s_u[k][ 9][4];
        float4 c3a = *(const float4*)&s_u[k][ 8][0], c3b = *(const float4*)&s_u[k][ 8][4];
        float4 c4a = *(const float4*)&s_u[k][ 7][0], c4b = *(const float4*)&s_u[k][ 7][4];
        float4 c5a = *(const float4*)&s_u[k][ 6][0], c5b = *(const float4*)&s_u[k][ 6][4];

        // phase 1 (L_A): reg 11,10,9; DPP m1->w8, m2->w7; LDS m4->w6
        REG_GATE_C(0, c0a, c0b)
        REG_GATE_C(1, c1a, c1b)
        REG_GATE_C(2, c2a, c2b)
        DPP_GATE_C(1, c3a, c3b, DPP_XOR1)
        DPP_GATE_C(2, c4a, c4b, DPP_XOR2)
        SHUF_GATE_C(4, c5a, c5b)

        // dump A-image (b128)
        #pragma unroll
        for (int i = 0; i < 4; ++i)
            ((float4*)buf0)[baseA4 ^ i] =
                make_float4(a[2*i].x, a[2*i].y, a[2*i+1].x, a[2*i+1].y);
        __syncthreads();                                   // B1

        // capture step k-1 readout into s_zk (no global stores in loop)
        if (k > 0 && tid < NQ) {
            float s = 0.f;
            #pragma unroll
            for (int w2 = 0; w2 < 8; ++w2) s += s_red[w2][tid];
            s_zk[k-1][tid] = s;
        }

        // gather L_E'
        #pragma unroll
        for (int r = 0; r < 8; ++r) a[r] = buf0[addrE[r]];

        // hoist phase-2 coefficients (wires 2,1,0,5,4,3)
        float4 d0a = *(const float4*)&s_u[k][2][0], d0b = *(const float4*)&s_u[k][2][4];
        float4 d1a = *(const float4*)&s_u[k][1][0], d1b = *(const float4*)&s_u[k][1][4];
        float4 d2a = *(const float4*)&s_u[k][0][0], d2b = *(const float4*)&s_u[k][0][4];
        float4 d3a = *(const float4*)&s_u[k][5][0], d3b = *(const float4*)&s_u[k][5][4];
        float4 d4a = *(const float4*)&s_u[k][4][0], d4b = *(const float4*)&s_u[k][4][4];
        float4 d5a = *(const float4*)&s_u[k][3][0], d5b = *(const float4*)&s_u[k][3][4];

        // phase 2 (L_E'): reg 2,1,0; DPP m1->w5, m2->w4; LDS m4->w3
        REG_GATE_C(0, d0a, d0b)
        REG_GATE_C(1, d1a, d1b)
        REG_GATE_C(2, d2a, d2b)
        DPP_GATE_C(1, d3a, d3b, DPP_XOR1)
        DPP_GATE_C(2, d4a, d4b, DPP_XOR2)
        SHUF_GATE_C(4, d5a, d5b)

        // CNOT-ring permutation scatter
        #pragma unroll
        for (int r = 0; r < 8; ++r) buf1[idxP[r]] = a[r];
        __syncthreads();                                   // B2
        #pragma unroll
        for (int i = 0; i < 4; ++i) {
            float4 v = ((float4*)buf1)[baseA4 ^ i];
            a[2*i]   = make_float2(v.x, v.y);
            a[2*i+1] = make_float2(v.z, v.w);
        }
    }

    // final expvals (post-ring of step KS-1)
    expval_LA(a, lane, wave, s_red);
    __syncthreads();
    if (tid < NQ) {
        float s = 0.f;
        #pragma unroll
        for (int w2 = 0; w2 < 8; ++w2) s += s_red[w2][tid];
        s_zk[KS-1][tid] = s;
    }
    __syncthreads();

    // ---------------- all global output stores, once ----------------
    if (tid < NQ) {
        #pragma unroll
        for (int k = 0; k < KS; ++k)
            readouts[(k * BB + b) * NQ + tid] = s_zk[k][tid];
    }
    if (tid < KS * 8) {
        int k = tid >> 3, c = tid & 7;
        float acc2 = s_hb[c];
        #pragma unroll
        for (int i = 0; i < NQ; ++i)
            acc2 = fmaf(s_zk[k][i], s_hw[c * NQ + i], acc2);
        logits[(k * BB + b) * 8 + c] = acc2;
        if (k == KS - 1) last[b * 8 + c] = acc2;
    }
}

extern "C" void kernel_launch(void* const* d_in, const int* in_sizes, int n_in,
                              void* d_out, int out_size, void* d_ws, size_t ws_size,
                              hipStream_t stream) {
    const int*   ids   = (const int*)d_in[0];
    const int*   mask  = (const int*)d_in[1];
    const float* emb   = (const float*)d_in[2];
    const float* pw    = (const float*)d_in[3];
    const float* pb    = (const float*)d_in[4];
    const float* theta = (const float*)d_in[5];
    const float* hw    = (const float*)d_in[6];
    const float* hb    = (const float*)d_in[7];
    float* out = (float*)d_out;

    float* readouts = out + KS * BB * 8;              // [K,B,NQ]
    float* last     = out + KS * BB * 8 + KS * BB * NQ;

    fused_kernel<<<BB, 512, 0, stream>>>(ids, mask, emb, pw, pb, theta,
                                         hw, hb, readouts, out, last);
}